// Round 2
// baseline (1117.754 us; speedup 1.0000x reference)
//
#include <hip/hip_runtime.h>
#include <cstdint>
#include <cstddef>

// x: [512][64][1024], conv1: K=32 S=16 -> T=63, Cout=256
// z1/z2 layout: [n][t][c] flat = (n*63+t)*256 + c   (== GEMM C row-major)

// ---------------------------------------------------------------------------
// K0: prep — fold BN into alpha/beta, transpose w1 -> w1T[c][o],
//     transpose conv2_w -> w2cT[(dt*256+c)*256 + o]
// ---------------------------------------------------------------------------
__global__ __launch_bounds__(256) void prep_kernel(
    const float* __restrict__ c1b, const float* __restrict__ g1,
    const float* __restrict__ b1,  const float* __restrict__ m1,
    const float* __restrict__ v1,
    const float* __restrict__ c2w, const float* __restrict__ c2b,
    const float* __restrict__ g2,  const float* __restrict__ b2,
    const float* __restrict__ m2,  const float* __restrict__ v2,
    const float* __restrict__ w1,
    float* __restrict__ w1T, float* __restrict__ w2cT,
    float* __restrict__ ab1, float* __restrict__ ab2)
{
    const int id = blockIdx.x * 256 + threadIdx.x;   // 65536 total
    if (id < 256) {
        float a1 = g1[id] / sqrtf(v1[id] + 1e-5f);
        ab1[id]       = a1;
        ab1[256 + id] = (c1b[id] - m1[id]) * a1 + b1[id];
        float a2 = g2[id] / sqrtf(v2[id] + 1e-5f);
        ab2[id]       = a2;
        ab2[256 + id] = (c2b[id] - m2[id]) * a2 + b2[id];
    }
    {   // w1T[c*256+o] = w1[o*256+c]
        const int c = id >> 8, o = id & 255;
        w1T[id] = w1[o * 256 + c];
    }
    for (int idx = id; idx < 3 * 256 * 256; idx += 65536) {
        const int o   = idx & 255;
        const int kap = idx >> 8;      // dt*256 + c
        const int dt  = kap >> 8;
        const int c   = kap & 255;
        w2cT[idx] = c2w[o * 768 + c * 3 + dt];
    }
}

// ---------------------------------------------------------------------------
// K1: conv1 + bn1 as tiled fp32 GEMM.  M=32256 (n,t), K=2048 (c*32+k), N=256 (o)
// 128x128x16 tile, 256 threads, 8x8/thread as 2x(4)+2x(4) fragments
// (conflict-free LDS reads), double-buffered LDS.
// ---------------------------------------------------------------------------
__global__ __launch_bounds__(256) void conv1_gemm(
    const float* __restrict__ x, const float* __restrict__ w1c,
    const float* __restrict__ ab, float* __restrict__ z1)
{
    __shared__ float As[2][16][128];
    __shared__ float Bs[2][16][128];
    const int tid = threadIdx.x;
    const int bm  = blockIdx.x;        // 0..251
    const int bn  = blockIdx.y;        // 0..1

    const int lr  = tid & 127;
    const int lkq = tid >> 7;          // 0..1
    const int am  = bm * 128 + lr;
    const int an  = am / 63;
    const int at  = am - an * 63;
    const float* arow = x + (size_t)an * 65536 + at * 16;   // + c0*1024 + k
    const float* brow = w1c + (size_t)(bn * 128 + lr) * 2048;

    const int tx = tid & 15, ty = tid >> 4;

    float4 la[2], lb[2];
#pragma unroll
    for (int q = 0; q < 2; ++q) {          // tile 0: kap0 = 0
        const int kq = lkq + 2 * q;
        la[q] = *(const float4*)(arow + kq * 4);
        lb[q] = *(const float4*)(brow + kq * 4);
    }
#pragma unroll
    for (int q = 0; q < 2; ++q) {
        const int kq = lkq + 2 * q;
        As[0][kq*4+0][lr] = la[q].x; As[0][kq*4+1][lr] = la[q].y;
        As[0][kq*4+2][lr] = la[q].z; As[0][kq*4+3][lr] = la[q].w;
        Bs[0][kq*4+0][lr] = lb[q].x; Bs[0][kq*4+1][lr] = lb[q].y;
        Bs[0][kq*4+2][lr] = lb[q].z; Bs[0][kq*4+3][lr] = lb[q].w;
    }
    __syncthreads();

    float acc[8][8] = {};
    int cur = 0;
    for (int it = 0; it < 128; ++it) {
        if (it + 1 < 128) {
            const int kap0 = (it + 1) * 16;
            const int aoff = (kap0 >> 5) * 1024 + (kap0 & 31);  // c0*1024 + k0
            const int boff = (kap0 >> 5) * 32   + (kap0 & 31);  // c0*32 + k0
#pragma unroll
            for (int q = 0; q < 2; ++q) {
                const int kq = lkq + 2 * q;
                la[q] = *(const float4*)(arow + aoff + kq * 4);
                lb[q] = *(const float4*)(brow + boff + kq * 4);
            }
        }
#pragma unroll
        for (int k = 0; k < 16; ++k) {
            float a[8], b[8];
            *(float4*)&a[0] = *(const float4*)&As[cur][k][tx*4];
            *(float4*)&a[4] = *(const float4*)&As[cur][k][64 + tx*4];
            *(float4*)&b[0] = *(const float4*)&Bs[cur][k][ty*4];
            *(float4*)&b[4] = *(const float4*)&Bs[cur][k][64 + ty*4];
#pragma unroll
            for (int i = 0; i < 8; ++i)
#pragma unroll
                for (int j = 0; j < 8; ++j)
                    acc[i][j] += a[i] * b[j];
        }
        if (it + 1 < 128) {
            const int nxt = cur ^ 1;
#pragma unroll
            for (int q = 0; q < 2; ++q) {
                const int kq = lkq + 2 * q;
                As[nxt][kq*4+0][lr] = la[q].x; As[nxt][kq*4+1][lr] = la[q].y;
                As[nxt][kq*4+2][lr] = la[q].z; As[nxt][kq*4+3][lr] = la[q].w;
                Bs[nxt][kq*4+0][lr] = lb[q].x; Bs[nxt][kq*4+1][lr] = lb[q].y;
                Bs[nxt][kq*4+2][lr] = lb[q].z; Bs[nxt][kq*4+3][lr] = lb[q].w;
            }
            cur = nxt;
        }
        __syncthreads();
    }

    const int rm[2] = { bm * 128 + tx * 4, bm * 128 + 64 + tx * 4 };
    const int cn[2] = { bn * 128 + ty * 4, bn * 128 + 64 + ty * 4 };
    float al[8], be[8];
#pragma unroll
    for (int jh = 0; jh < 2; ++jh)
#pragma unroll
        for (int jj = 0; jj < 4; ++jj) {
            al[jh*4+jj] = ab[cn[jh] + jj];
            be[jh*4+jj] = ab[256 + cn[jh] + jj];
        }
#pragma unroll
    for (int ih = 0; ih < 2; ++ih)
#pragma unroll
        for (int ii = 0; ii < 4; ++ii) {
            const int i  = ih * 4 + ii;
            const int gm = rm[ih] + ii;
            float4 v0, v1;
            v0.x = acc[i][0]*al[0]+be[0]; v0.y = acc[i][1]*al[1]+be[1];
            v0.z = acc[i][2]*al[2]+be[2]; v0.w = acc[i][3]*al[3]+be[3];
            v1.x = acc[i][4]*al[4]+be[4]; v1.y = acc[i][5]*al[5]+be[5];
            v1.z = acc[i][6]*al[6]+be[6]; v1.w = acc[i][7]*al[7]+be[7];
            *(float4*)(z1 + (size_t)gm * 256 + cn[0]) = v0;
            *(float4*)(z1 + (size_t)gm * 256 + cn[1]) = v1;
        }
}

// ---------------------------------------------------------------------------
// K2: conv2 + bn2 as tiled fp32 GEMM.  K=768 (dt*256+c), zero-padded halo in t.
// Same structure as K1.
// ---------------------------------------------------------------------------
__global__ __launch_bounds__(256) void conv2_gemm(
    const float* __restrict__ z1, const float* __restrict__ w2cT,
    const float* __restrict__ ab, float* __restrict__ z2)
{
    __shared__ float As[2][16][128];
    __shared__ float Bs[2][16][128];
    const int tid = threadIdx.x;
    const int bm  = blockIdx.x;
    const int bn  = blockIdx.y;

    const int lr  = tid & 127;
    const int lkq = tid >> 7;
    const int am  = bm * 128 + lr;
    const int an  = am / 63;
    const int at  = am - an * 63;
    const float* abase = z1 + (size_t)an * 16128;

    const int boq  = tid & 31;          // o-quad 0..31
    const int bk   = tid >> 5;          // 0..7
    const int go0b = bn * 128 + boq * 4;

    const int tx = tid & 15, ty = tid >> 4;

    float4 la[2], lb[2];
    int lkk[2];
    auto stage_load = [&](int it) {
        const int kap0 = it * 16;
        const int dt   = kap0 >> 8;     // 0..2
        const int c0   = kap0 & 255;
        const int trow = at + dt - 1;
        const bool valid = (trow >= 0) && (trow < 63);
        const float* arow = abase + trow * 256 + c0;
#pragma unroll
        for (int q = 0; q < 2; ++q) {
            const int kq = lkq + 2 * q;
            float4 av = make_float4(0.f, 0.f, 0.f, 0.f);
            if (valid) av = *(const float4*)(arow + kq * 4);
            la[q] = av;
            const int kk = bk + 8 * q;
            lkk[q] = kk;
            lb[q] = *(const float4*)(w2cT + (size_t)(kap0 + kk) * 256 + go0b);
        }
    };
    auto stage_store = [&](int buf) {
#pragma unroll
        for (int q = 0; q < 2; ++q) {
            const int kq = lkq + 2 * q;
            As[buf][kq*4+0][lr] = la[q].x; As[buf][kq*4+1][lr] = la[q].y;
            As[buf][kq*4+2][lr] = la[q].z; As[buf][kq*4+3][lr] = la[q].w;
            *(float4*)&Bs[buf][lkk[q]][boq * 4] = lb[q];
        }
    };

    stage_load(0);
    stage_store(0);
    __syncthreads();

    float acc[8][8] = {};
    int cur = 0;
    for (int it = 0; it < 48; ++it) {
        if (it + 1 < 48) stage_load(it + 1);
#pragma unroll
        for (int k = 0; k < 16; ++k) {
            float a[8], b[8];
            *(float4*)&a[0] = *(const float4*)&As[cur][k][tx*4];
            *(float4*)&a[4] = *(const float4*)&As[cur][k][64 + tx*4];
            *(float4*)&b[0] = *(const float4*)&Bs[cur][k][ty*4];
            *(float4*)&b[4] = *(const float4*)&Bs[cur][k][64 + ty*4];
#pragma unroll
            for (int i = 0; i < 8; ++i)
#pragma unroll
                for (int j = 0; j < 8; ++j)
                    acc[i][j] += a[i] * b[j];
        }
        if (it + 1 < 48) {
            const int nxt = cur ^ 1;
            stage_store(nxt);
            cur = nxt;
        }
        __syncthreads();
    }

    const int rm[2] = { bm * 128 + tx * 4, bm * 128 + 64 + tx * 4 };
    const int cn[2] = { bn * 128 + ty * 4, bn * 128 + 64 + ty * 4 };
    float al[8], be[8];
#pragma unroll
    for (int jh = 0; jh < 2; ++jh)
#pragma unroll
        for (int jj = 0; jj < 4; ++jj) {
            al[jh*4+jj] = ab[cn[jh] + jj];
            be[jh*4+jj] = ab[256 + cn[jh] + jj];
        }
#pragma unroll
    for (int ih = 0; ih < 2; ++ih)
#pragma unroll
        for (int ii = 0; ii < 4; ++ii) {
            const int i  = ih * 4 + ii;
            const int gm = rm[ih] + ii;
            float4 v0, v1;
            v0.x = acc[i][0]*al[0]+be[0]; v0.y = acc[i][1]*al[1]+be[1];
            v0.z = acc[i][2]*al[2]+be[2]; v0.w = acc[i][3]*al[3]+be[3];
            v1.x = acc[i][4]*al[4]+be[4]; v1.y = acc[i][5]*al[5]+be[5];
            v1.z = acc[i][6]*al[6]+be[6]; v1.w = acc[i][7]*al[7]+be[7];
            *(float4*)(z2 + (size_t)gm * 256 + cn[0]) = v0;
            *(float4*)(z2 + (size_t)gm * 256 + cn[1]) = v1;
        }
}

// ---------------------------------------------------------------------------
// K3: fused SNN tail, one block per n (256 threads). Unchanged from R1 (passed).
// ---------------------------------------------------------------------------
__global__ __launch_bounds__(256) void snn_fused(
    const float* __restrict__ z2, const float* __restrict__ w1T,
    const float* __restrict__ w2, float* __restrict__ out)
{
    __shared__ float Sc[256 * 16];
    __shared__ unsigned long long M2[256];
    __shared__ float Y[2 * 63];
    const int n   = blockIdx.x;
    const int tid = threadIdx.x;

    unsigned long long mask = 0ull;
    {
        float cur = 0.f, vol = 0.f;
        const float* zrow = z2 + (size_t)n * 16128 + tid;
        for (int t = 0; t < 63; ++t) {
            float xv = zrow[(size_t)t * 256];
            cur = 0.1f * cur + xv;
            vol = 0.1f * vol + cur;
            float u = vol - 0.3f;
            if (u >= 0.f) { mask |= (1ull << t); vol = 0.f; }
        }
    }

    unsigned long long mask2 = 0ull;
    float v2 = 0.f;
    for (int tc = 0; tc < 4; ++tc) {
        const int T0 = tc * 16;
        __syncthreads();
#pragma unroll
        for (int j4 = 0; j4 < 4; ++j4) {
            float4 f;
            f.x = ((mask >> (T0 + j4*4 + 0)) & 1ull) ? 1.f : 0.f;
            f.y = ((mask >> (T0 + j4*4 + 1)) & 1ull) ? 1.f : 0.f;
            f.z = ((mask >> (T0 + j4*4 + 2)) & 1ull) ? 1.f : 0.f;
            f.w = ((mask >> (T0 + j4*4 + 3)) & 1ull) ? 1.f : 0.f;
            *(float4*)&Sc[tid * 16 + j4 * 4] = f;
        }
        __syncthreads();
        float acc[16] = {};
        const float* wp = w1T + tid;
#pragma unroll 4
        for (int c = 0; c < 256; ++c) {
            float w = wp[(size_t)c * 256];
            const float* sp = &Sc[c * 16];
#pragma unroll
            for (int j = 0; j < 16; ++j) acc[j] += w * sp[j];
        }
        const int nT = (tc == 3) ? 15 : 16;
        for (int j = 0; j < nT; ++j) {
            v2 = 0.9f * v2 + acc[j];
            float u = v2 - 0.1f;
            if (u >= 0.f) { mask2 |= (1ull << (T0 + j)); v2 = 0.f; }
        }
    }
    __syncthreads();
    M2[tid] = mask2;
    __syncthreads();

    if (tid < 126) {
        const int cls = tid / 63;
        const int t   = tid - cls * 63;
        const float* wrow = w2 + cls * 256;
        float acc = 0.f;
#pragma unroll 4
        for (int o = 0; o < 256; ++o)
            acc += ((M2[o] >> t) & 1ull) ? wrow[o] : 0.f;
        Y[cls * 63 + t] = acc;
    }
    __syncthreads();
    if (tid < 2) {
        float v = 0.f;
        float* orow = out + (size_t)n * 126 + tid * 63;
        for (int t = 0; t < 63; ++t) {
            v = 0.9f * v + Y[tid * 63 + t];
            float u = v - 0.1f;
            float s = (u >= 0.f) ? 1.f : 0.f;
            orow[t] = s;
            v = (u >= 0.f) ? 0.f : v;
        }
    }
}

// ---------------------------------------------------------------------------
extern "C" void kernel_launch(void* const* d_in, const int* in_sizes, int n_in,
                              void* d_out, int out_size, void* d_ws, size_t ws_size,
                              hipStream_t stream)
{
    const float* x    = (const float*)d_in[0];
    const float* c1w  = (const float*)d_in[1];
    const float* c1b  = (const float*)d_in[2];
    const float* g1   = (const float*)d_in[3];
    const float* b1   = (const float*)d_in[4];
    const float* m1   = (const float*)d_in[5];
    const float* v1   = (const float*)d_in[6];
    const float* c2w  = (const float*)d_in[7];
    const float* c2b  = (const float*)d_in[8];
    const float* g2   = (const float*)d_in[9];
    const float* b2   = (const float*)d_in[10];
    const float* m2   = (const float*)d_in[11];
    const float* v2   = (const float*)d_in[12];
    const float* w1   = (const float*)d_in[13];
    const float* w2   = (const float*)d_in[14];
    float* out = (float*)d_out;

    float* ws   = (float*)d_ws;
    float* z1   = ws;                      //  8,257,536 floats
    float* z2   = z1 + 8257536;            //  8,257,536
    float* w1T  = z2 + 8257536;            //     65,536
    float* w2cT = w1T + 65536;             //    196,608
    float* ab1  = w2cT + 196608;           //        512
    float* ab2  = ab1 + 512;               //        512

    prep_kernel<<<256, 256, 0, stream>>>(c1b, g1, b1, m1, v1,
                                         c2w, c2b, g2, b2, m2, v2,
                                         w1, w1T, w2cT, ab1, ab2);
    conv1_gemm<<<dim3(252, 2), 256, 0, stream>>>(x, c1w, ab1, z1);
    conv2_gemm<<<dim3(252, 2), 256, 0, stream>>>(z1, w2cT, ab2, z2);
    snn_fused<<<512, 256, 0, stream>>>(z2, w1T, w2, out);
}

// Round 3
// 483.586 us; speedup vs baseline: 2.3114x; 2.3114x over previous
//
#include <hip/hip_runtime.h>
#include <cstdint>
#include <cstddef>

// x: [512][64][1024], conv1: K=32 S=16 -> T=63, Cout=256
// z layout: [n][t][c] flat = (n*63+t)*256 + c
// fp16 2-limb: v ~= hi + lo*(1/2048), hi=fp16(v), lo=fp16((v-hi)*2048)

typedef _Float16 half8 __attribute__((ext_vector_type(8)));
typedef float floatx4 __attribute__((ext_vector_type(4)));

__device__ __forceinline__ void split_f32(float v, _Float16& hi, _Float16& lo) {
    _Float16 h = (_Float16)v;
    hi = h;
    lo = (_Float16)((v - (float)h) * 2048.0f);
}

// ---------------------------------------------------------------------------
// K0: prep — BN fold, w1T (snn), fp16 limb splits of conv1_w and conv2_w(T)
// ---------------------------------------------------------------------------
__global__ __launch_bounds__(256) void prep_kernel(
    const float* __restrict__ c1w, const float* __restrict__ c1b,
    const float* __restrict__ g1,  const float* __restrict__ b1,
    const float* __restrict__ m1,  const float* __restrict__ v1,
    const float* __restrict__ c2w, const float* __restrict__ c2b,
    const float* __restrict__ g2,  const float* __restrict__ b2,
    const float* __restrict__ m2,  const float* __restrict__ v2,
    const float* __restrict__ w1,
    float* __restrict__ w1T,
    _Float16* __restrict__ w1h, _Float16* __restrict__ w1l,
    _Float16* __restrict__ w2h, _Float16* __restrict__ w2l,
    float* __restrict__ ab1, float* __restrict__ ab2)
{
    const int id = blockIdx.x * 256 + threadIdx.x;   // 65536 total
    if (id < 256) {
        float a1 = g1[id] / sqrtf(v1[id] + 1e-5f);
        ab1[id]       = a1;
        ab1[256 + id] = (c1b[id] - m1[id]) * a1 + b1[id];
        float a2 = g2[id] / sqrtf(v2[id] + 1e-5f);
        ab2[id]       = a2;
        ab2[256 + id] = (c2b[id] - m2[id]) * a2 + b2[id];
    }
    {   // w1T[c*256+o] = w1[o*256+c]  (for snn dense1)
        const int c = id >> 8, o = id & 255;
        w1T[id] = w1[o * 256 + c];
    }
    // conv1_w limbs: [o][2048] direct layout
    for (int idx = id; idx < 256 * 2048; idx += 65536)
        split_f32(c1w[idx], w1h[idx], w1l[idx]);
    // conv2_w limbs transposed to [o][dt*256+c]
    for (int idx = id; idx < 256 * 768; idx += 65536) {
        const int o  = idx / 768;
        const int r  = idx - o * 768;
        const int dt = r >> 8;
        const int c  = r & 255;
        split_f32(c2w[o * 768 + c * 3 + dt], w2h[idx], w2l[idx]);
    }
}

// ---------------------------------------------------------------------------
// K1: conv1 + bn1, fp16 2-limb MFMA GEMM. M=32256, K=2048 (c*32+k), N=256.
// 128x128 tile, BK=32, 4 waves (2x2), each 64x64 via 4x4 mfma_16x16x32_f16.
// Output: z1 as fp16 limb pair (for conv2 A-operand).
// ---------------------------------------------------------------------------
__global__ __launch_bounds__(256, 2) void conv1_mfma(
    const float* __restrict__ x,
    const _Float16* __restrict__ w1h, const _Float16* __restrict__ w1l,
    const float* __restrict__ ab,
    _Float16* __restrict__ z1h, _Float16* __restrict__ z1l)
{
    __shared__ _Float16 Ah[4][128][8];   // [k-quad][m][8] fragment-major
    __shared__ _Float16 Al[4][128][8];
    __shared__ _Float16 Bh[4][128][8];
    __shared__ _Float16 Bl[4][128][8];

    const int tid = threadIdx.x;
    const int bm = blockIdx.x, bn = blockIdx.y;
    const int lr = tid & 127;          // staging row
    const int h  = tid >> 7;           // k-half 0..1

    const int am = bm * 128 + lr;
    const int an = am / 63, at = am - an * 63;
    const float*    arow  = x   + (size_t)an * 65536 + at * 16 + h * 16;
    const _Float16* bhrow = w1h + (size_t)(bn * 128 + lr) * 2048 + h * 16;
    const _Float16* blrow = w1l + (size_t)(bn * 128 + lr) * 2048 + h * 16;

    const int lane = tid & 63;
    const int wv   = tid >> 6;
    const int mw   = wv & 1, nw = wv >> 1;
    const int quad = lane >> 4;
    const int l15  = lane & 15;

    floatx4 accA[4][4] = {};
    floatx4 accB[4][4] = {};

    for (int it = 0; it < 64; ++it) {
        const float* ap = arow + it * 1024;       // channel c = it
        float va[16];
        *(float4*)&va[0]  = *(const float4*)(ap);
        *(float4*)&va[4]  = *(const float4*)(ap + 4);
        *(float4*)&va[8]  = *(const float4*)(ap + 8);
        *(float4*)&va[12] = *(const float4*)(ap + 12);
        int4 bh0 = *(const int4*)(bhrow + it * 32);
        int4 bh1 = *(const int4*)(bhrow + it * 32 + 8);
        int4 bl0 = *(const int4*)(blrow + it * 32);
        int4 bl1 = *(const int4*)(blrow + it * 32 + 8);

        union U { _Float16 hf[8]; int4 v; };
        U c0h, c0l, c1h, c1l;
#pragma unroll
        for (int j = 0; j < 8; ++j) split_f32(va[j],     c0h.hf[j], c0l.hf[j]);
#pragma unroll
        for (int j = 0; j < 8; ++j) split_f32(va[8 + j], c1h.hf[j], c1l.hf[j]);

        __syncthreads();               // prior iter's fragment reads done
        *(int4*)&Ah[2*h  ][lr][0] = c0h.v;
        *(int4*)&Ah[2*h+1][lr][0] = c1h.v;
        *(int4*)&Al[2*h  ][lr][0] = c0l.v;
        *(int4*)&Al[2*h+1][lr][0] = c1l.v;
        *(int4*)&Bh[2*h  ][lr][0] = bh0;
        *(int4*)&Bh[2*h+1][lr][0] = bh1;
        *(int4*)&Bl[2*h  ][lr][0] = bl0;
        *(int4*)&Bl[2*h+1][lr][0] = bl1;
        __syncthreads();

        half8 fah[4], fal[4], fbh[4], fbl[4];
#pragma unroll
        for (int t = 0; t < 4; ++t) {
            fah[t] = *(const half8*)&Ah[quad][mw*64 + t*16 + l15][0];
            fal[t] = *(const half8*)&Al[quad][mw*64 + t*16 + l15][0];
            fbh[t] = *(const half8*)&Bh[quad][nw*64 + t*16 + l15][0];
            fbl[t] = *(const half8*)&Bl[quad][nw*64 + t*16 + l15][0];
        }
#pragma unroll
        for (int ti = 0; ti < 4; ++ti)
#pragma unroll
            for (int tj = 0; tj < 4; ++tj) {
                accA[ti][tj] = __builtin_amdgcn_mfma_f32_16x16x32_f16(fah[ti], fbh[tj], accA[ti][tj], 0, 0, 0);
                accB[ti][tj] = __builtin_amdgcn_mfma_f32_16x16x32_f16(fah[ti], fbl[tj], accB[ti][tj], 0, 0, 0);
                accB[ti][tj] = __builtin_amdgcn_mfma_f32_16x16x32_f16(fal[ti], fbh[tj], accB[ti][tj], 0, 0, 0);
            }
    }

    // epilogue: C/D layout col=lane&15 (n), row=quad*4+reg (m)
#pragma unroll
    for (int tj = 0; tj < 4; ++tj) {
        const int o = bn*128 + nw*64 + tj*16 + l15;
        const float alpha = ab[o], beta = ab[256 + o];
#pragma unroll
        for (int ti = 0; ti < 4; ++ti) {
            const int m0 = bm*128 + mw*64 + ti*16 + quad*4;
#pragma unroll
            for (int r = 0; r < 4; ++r) {
                float c = accA[ti][tj][r] + accB[ti][tj][r] * (1.0f/2048.0f);
                float z = c * alpha + beta;
                _Float16 zh, zl;
                split_f32(z, zh, zl);
                const size_t off = (size_t)(m0 + r) * 256 + o;
                z1h[off] = zh;
                z1l[off] = zl;
            }
        }
    }
}

// ---------------------------------------------------------------------------
// K2: conv2 + bn2, fp16 2-limb MFMA GEMM. K=768 (dt*256+c), halo zero-fill.
// A = z1 limbs (preconverted), B = w2 limbs. Output z2 fp32.
// ---------------------------------------------------------------------------
__global__ __launch_bounds__(256, 2) void conv2_mfma(
    const _Float16* __restrict__ z1h, const _Float16* __restrict__ z1l,
    const _Float16* __restrict__ w2h, const _Float16* __restrict__ w2l,
    const float* __restrict__ ab, float* __restrict__ z2)
{
    __shared__ _Float16 Ah[4][128][8];
    __shared__ _Float16 Al[4][128][8];
    __shared__ _Float16 Bh[4][128][8];
    __shared__ _Float16 Bl[4][128][8];

    const int tid = threadIdx.x;
    const int bm = blockIdx.x, bn = blockIdx.y;
    const int lr = tid & 127;
    const int h  = tid >> 7;

    const int am = bm * 128 + lr;
    const int an = am / 63, at = am - an * 63;
    const _Float16* abase_h = z1h + (size_t)an * 16128;
    const _Float16* abase_l = z1l + (size_t)an * 16128;
    const _Float16* bhrow = w2h + (size_t)(bn * 128 + lr) * 768 + h * 16;
    const _Float16* blrow = w2l + (size_t)(bn * 128 + lr) * 768 + h * 16;

    const int lane = tid & 63;
    const int wv   = tid >> 6;
    const int mw   = wv & 1, nw = wv >> 1;
    const int quad = lane >> 4;
    const int l15  = lane & 15;

    floatx4 accA[4][4] = {};
    floatx4 accB[4][4] = {};

    const int4 z4 = {0, 0, 0, 0};

    for (int it = 0; it < 24; ++it) {
        const int kap0 = it * 32;
        const int dt   = kap0 >> 8;    // 0..2
        const int c0   = kap0 & 255;
        const int trow = at + dt - 1;
        const bool valid = (trow >= 0) && (trow < 63);
        const _Float16* aph = abase_h + trow * 256 + c0 + h * 16;
        const _Float16* apl = abase_l + trow * 256 + c0 + h * 16;
        int4 a0h = valid ? *(const int4*)(aph)     : z4;
        int4 a1h = valid ? *(const int4*)(aph + 8) : z4;
        int4 a0l = valid ? *(const int4*)(apl)     : z4;
        int4 a1l = valid ? *(const int4*)(apl + 8) : z4;
        int4 b0h = *(const int4*)(bhrow + kap0);
        int4 b1h = *(const int4*)(bhrow + kap0 + 8);
        int4 b0l = *(const int4*)(blrow + kap0);
        int4 b1l = *(const int4*)(blrow + kap0 + 8);

        __syncthreads();
        *(int4*)&Ah[2*h  ][lr][0] = a0h;
        *(int4*)&Ah[2*h+1][lr][0] = a1h;
        *(int4*)&Al[2*h  ][lr][0] = a0l;
        *(int4*)&Al[2*h+1][lr][0] = a1l;
        *(int4*)&Bh[2*h  ][lr][0] = b0h;
        *(int4*)&Bh[2*h+1][lr][0] = b1h;
        *(int4*)&Bl[2*h  ][lr][0] = b0l;
        *(int4*)&Bl[2*h+1][lr][0] = b1l;
        __syncthreads();

        half8 fah[4], fal[4], fbh[4], fbl[4];
#pragma unroll
        for (int t = 0; t < 4; ++t) {
            fah[t] = *(const half8*)&Ah[quad][mw*64 + t*16 + l15][0];
            fal[t] = *(const half8*)&Al[quad][mw*64 + t*16 + l15][0];
            fbh[t] = *(const half8*)&Bh[quad][nw*64 + t*16 + l15][0];
            fbl[t] = *(const half8*)&Bl[quad][nw*64 + t*16 + l15][0];
        }
#pragma unroll
        for (int ti = 0; ti < 4; ++ti)
#pragma unroll
            for (int tj = 0; tj < 4; ++tj) {
                accA[ti][tj] = __builtin_amdgcn_mfma_f32_16x16x32_f16(fah[ti], fbh[tj], accA[ti][tj], 0, 0, 0);
                accB[ti][tj] = __builtin_amdgcn_mfma_f32_16x16x32_f16(fah[ti], fbl[tj], accB[ti][tj], 0, 0, 0);
                accB[ti][tj] = __builtin_amdgcn_mfma_f32_16x16x32_f16(fal[ti], fbh[tj], accB[ti][tj], 0, 0, 0);
            }
    }

#pragma unroll
    for (int tj = 0; tj < 4; ++tj) {
        const int o = bn*128 + nw*64 + tj*16 + l15;
        const float alpha = ab[o], beta = ab[256 + o];
#pragma unroll
        for (int ti = 0; ti < 4; ++ti) {
            const int m0 = bm*128 + mw*64 + ti*16 + quad*4;
#pragma unroll
            for (int r = 0; r < 4; ++r) {
                float c = accA[ti][tj][r] + accB[ti][tj][r] * (1.0f/2048.0f);
                z2[(size_t)(m0 + r) * 256 + o] = c * alpha + beta;
            }
        }
    }
}

// ---------------------------------------------------------------------------
// K3: fused SNN tail, one block per n (256 threads). Unchanged (passed R1/R2).
// ---------------------------------------------------------------------------
__global__ __launch_bounds__(256) void snn_fused(
    const float* __restrict__ z2, const float* __restrict__ w1T,
    const float* __restrict__ w2, float* __restrict__ out)
{
    __shared__ float Sc[256 * 16];
    __shared__ unsigned long long M2[256];
    __shared__ float Y[2 * 63];
    const int n   = blockIdx.x;
    const int tid = threadIdx.x;

    unsigned long long mask = 0ull;
    {
        float cur = 0.f, vol = 0.f;
        const float* zrow = z2 + (size_t)n * 16128 + tid;
        for (int t = 0; t < 63; ++t) {
            float xv = zrow[(size_t)t * 256];
            cur = 0.1f * cur + xv;
            vol = 0.1f * vol + cur;
            float u = vol - 0.3f;
            if (u >= 0.f) { mask |= (1ull << t); vol = 0.f; }
        }
    }

    unsigned long long mask2 = 0ull;
    float v2 = 0.f;
    for (int tc = 0; tc < 4; ++tc) {
        const int T0 = tc * 16;
        __syncthreads();
#pragma unroll
        for (int j4 = 0; j4 < 4; ++j4) {
            float4 f;
            f.x = ((mask >> (T0 + j4*4 + 0)) & 1ull) ? 1.f : 0.f;
            f.y = ((mask >> (T0 + j4*4 + 1)) & 1ull) ? 1.f : 0.f;
            f.z = ((mask >> (T0 + j4*4 + 2)) & 1ull) ? 1.f : 0.f;
            f.w = ((mask >> (T0 + j4*4 + 3)) & 1ull) ? 1.f : 0.f;
            *(float4*)&Sc[tid * 16 + j4 * 4] = f;
        }
        __syncthreads();
        float acc[16] = {};
        const float* wp = w1T + tid;
#pragma unroll 4
        for (int c = 0; c < 256; ++c) {
            float w = wp[(size_t)c * 256];
            const float* sp = &Sc[c * 16];
#pragma unroll
            for (int j = 0; j < 16; ++j) acc[j] += w * sp[j];
        }
        const int nT = (tc == 3) ? 15 : 16;
        for (int j = 0; j < nT; ++j) {
            v2 = 0.9f * v2 + acc[j];
            float u = v2 - 0.1f;
            if (u >= 0.f) { mask2 |= (1ull << (T0 + j)); v2 = 0.f; }
        }
    }
    __syncthreads();
    M2[tid] = mask2;
    __syncthreads();

    if (tid < 126) {
        const int cls = tid / 63;
        const int t   = tid - cls * 63;
        const float* wrow = w2 + cls * 256;
        float acc = 0.f;
#pragma unroll 4
        for (int o = 0; o < 256; ++o)
            acc += ((M2[o] >> t) & 1ull) ? wrow[o] : 0.f;
        Y[cls * 63 + t] = acc;
    }
    __syncthreads();
    if (tid < 2) {
        float v = 0.f;
        float* orow = out + (size_t)n * 126 + tid * 63;
        for (int t = 0; t < 63; ++t) {
            v = 0.9f * v + Y[tid * 63 + t];
            float u = v - 0.1f;
            float s = (u >= 0.f) ? 1.f : 0.f;
            orow[t] = s;
            v = (u >= 0.f) ? 0.f : v;
        }
    }
}

// ---------------------------------------------------------------------------
extern "C" void kernel_launch(void* const* d_in, const int* in_sizes, int n_in,
                              void* d_out, int out_size, void* d_ws, size_t ws_size,
                              hipStream_t stream)
{
    const float* x    = (const float*)d_in[0];
    const float* c1w  = (const float*)d_in[1];
    const float* c1b  = (const float*)d_in[2];
    const float* g1   = (const float*)d_in[3];
    const float* b1   = (const float*)d_in[4];
    const float* m1   = (const float*)d_in[5];
    const float* v1   = (const float*)d_in[6];
    const float* c2w  = (const float*)d_in[7];
    const float* c2b  = (const float*)d_in[8];
    const float* g2   = (const float*)d_in[9];
    const float* b2   = (const float*)d_in[10];
    const float* m2   = (const float*)d_in[11];
    const float* v2   = (const float*)d_in[12];
    const float* w1   = (const float*)d_in[13];
    const float* w2   = (const float*)d_in[14];
    float* out = (float*)d_out;

    float* ws = (float*)d_ws;
    float*    z2  = ws;                               // 8,257,536 f
    _Float16* z1h = (_Float16*)(z2 + 8257536);        // 8,257,536 h = 4,128,768 f
    _Float16* z1l = (_Float16*)(z2 + 8257536 + 4128768);
    float*    w1T = z2 + 8257536 + 2 * 4128768;       // 65,536 f
    _Float16* w1h = (_Float16*)(w1T + 65536);         // 524,288 h = 262,144 f
    _Float16* w1l = (_Float16*)(w1T + 65536 + 262144);
    _Float16* w2h = (_Float16*)(w1T + 65536 + 2 * 262144);          // 196,608 h = 98,304 f
    _Float16* w2l = (_Float16*)(w1T + 65536 + 2 * 262144 + 98304);
    float*    ab1 = w1T + 65536 + 2 * 262144 + 2 * 98304;
    float*    ab2 = ab1 + 512;

    prep_kernel<<<256, 256, 0, stream>>>(c1w, c1b, g1, b1, m1, v1,
                                         c2w, c2b, g2, b2, m2, v2,
                                         w1, w1T, w1h, w1l, w2h, w2l, ab1, ab2);
    conv1_mfma<<<dim3(252, 2), 256, 0, stream>>>(x, w1h, w1l, ab1, z1h, z1l);
    conv2_mfma<<<dim3(252, 2), 256, 0, stream>>>(z1h, z1l, w2h, w2l, ab2, z2);
    snn_fused<<<512, 256, 0, stream>>>(z2, w1T, w2, out);
}

// Round 4
// 433.261 us; speedup vs baseline: 2.5799x; 1.1162x over previous
//
#include <hip/hip_runtime.h>
#include <cstdint>
#include <cstddef>

// x: [512][64][1024], conv1: K=32 S=16 -> T=63, Cout=256
// z layout: [n][t][c] flat = (n*63+t)*256 + c
// fp16 2-limb: v ~= hi + lo*(1/2048), hi=fp16(v), lo=fp16((v-hi)*2048)

typedef _Float16 half8 __attribute__((ext_vector_type(8)));
typedef float floatx4 __attribute__((ext_vector_type(4)));

__device__ __forceinline__ void split_f32(float v, _Float16& hi, _Float16& lo) {
    _Float16 h = (_Float16)v;
    hi = h;
    lo = (_Float16)((v - (float)h) * 2048.0f);
}

// ---------------------------------------------------------------------------
// K0: prep — BN fold, fp16 limb splits of conv1_w, conv2_w(T), w1 (dense1)
// ---------------------------------------------------------------------------
__global__ __launch_bounds__(256) void prep_kernel(
    const float* __restrict__ c1w, const float* __restrict__ c1b,
    const float* __restrict__ g1,  const float* __restrict__ b1,
    const float* __restrict__ m1,  const float* __restrict__ v1,
    const float* __restrict__ c2w, const float* __restrict__ c2b,
    const float* __restrict__ g2,  const float* __restrict__ b2,
    const float* __restrict__ m2,  const float* __restrict__ v2,
    const float* __restrict__ w1,
    _Float16* __restrict__ w1h, _Float16* __restrict__ w1l,
    _Float16* __restrict__ w2h, _Float16* __restrict__ w2l,
    _Float16* __restrict__ wdh, _Float16* __restrict__ wdl,
    float* __restrict__ ab1, float* __restrict__ ab2)
{
    const int id = blockIdx.x * 256 + threadIdx.x;   // 65536 total
    if (id < 256) {
        float a1 = g1[id] / sqrtf(v1[id] + 1e-5f);
        ab1[id]       = a1;
        ab1[256 + id] = (c1b[id] - m1[id]) * a1 + b1[id];
        float a2 = g2[id] / sqrtf(v2[id] + 1e-5f);
        ab2[id]       = a2;
        ab2[256 + id] = (c2b[id] - m2[id]) * a2 + b2[id];
    }
    // dense1 weights: w1[o][c] row-major already == B-row layout [o][k=c]
    split_f32(w1[id], wdh[id], wdl[id]);
    // conv1_w limbs: [o][2048] direct layout
    for (int idx = id; idx < 256 * 2048; idx += 65536)
        split_f32(c1w[idx], w1h[idx], w1l[idx]);
    // conv2_w limbs transposed to [o][dt*256+c]
    for (int idx = id; idx < 256 * 768; idx += 65536) {
        const int o  = idx / 768;
        const int r  = idx - o * 768;
        const int dt = r >> 8;
        const int c  = r & 255;
        split_f32(c2w[o * 768 + c * 3 + dt], w2h[idx], w2l[idx]);
    }
}

// ---------------------------------------------------------------------------
// K1: conv1 + bn1, fp16 2-limb MFMA GEMM. M=32256, K=2048 (c*32+k), N=256.
// (unchanged from R3 — passed)
// ---------------------------------------------------------------------------
__global__ __launch_bounds__(256, 2) void conv1_mfma(
    const float* __restrict__ x,
    const _Float16* __restrict__ w1h, const _Float16* __restrict__ w1l,
    const float* __restrict__ ab,
    _Float16* __restrict__ z1h, _Float16* __restrict__ z1l)
{
    __shared__ _Float16 Ah[4][128][8];   // [k-quad][m][8] fragment-major
    __shared__ _Float16 Al[4][128][8];
    __shared__ _Float16 Bh[4][128][8];
    __shared__ _Float16 Bl[4][128][8];

    const int tid = threadIdx.x;
    const int bm = blockIdx.x, bn = blockIdx.y;
    const int lr = tid & 127;
    const int h  = tid >> 7;

    const int am = bm * 128 + lr;
    const int an = am / 63, at = am - an * 63;
    const float*    arow  = x   + (size_t)an * 65536 + at * 16 + h * 16;
    const _Float16* bhrow = w1h + (size_t)(bn * 128 + lr) * 2048 + h * 16;
    const _Float16* blrow = w1l + (size_t)(bn * 128 + lr) * 2048 + h * 16;

    const int lane = tid & 63;
    const int wv   = tid >> 6;
    const int mw   = wv & 1, nw = wv >> 1;
    const int quad = lane >> 4;
    const int l15  = lane & 15;

    floatx4 accA[4][4] = {};
    floatx4 accB[4][4] = {};

    for (int it = 0; it < 64; ++it) {
        const float* ap = arow + it * 1024;
        float va[16];
        *(float4*)&va[0]  = *(const float4*)(ap);
        *(float4*)&va[4]  = *(const float4*)(ap + 4);
        *(float4*)&va[8]  = *(const float4*)(ap + 8);
        *(float4*)&va[12] = *(const float4*)(ap + 12);
        int4 bh0 = *(const int4*)(bhrow + it * 32);
        int4 bh1 = *(const int4*)(bhrow + it * 32 + 8);
        int4 bl0 = *(const int4*)(blrow + it * 32);
        int4 bl1 = *(const int4*)(blrow + it * 32 + 8);

        union U { _Float16 hf[8]; int4 v; };
        U c0h, c0l, c1h, c1l;
#pragma unroll
        for (int j = 0; j < 8; ++j) split_f32(va[j],     c0h.hf[j], c0l.hf[j]);
#pragma unroll
        for (int j = 0; j < 8; ++j) split_f32(va[8 + j], c1h.hf[j], c1l.hf[j]);

        __syncthreads();
        *(int4*)&Ah[2*h  ][lr][0] = c0h.v;
        *(int4*)&Ah[2*h+1][lr][0] = c1h.v;
        *(int4*)&Al[2*h  ][lr][0] = c0l.v;
        *(int4*)&Al[2*h+1][lr][0] = c1l.v;
        *(int4*)&Bh[2*h  ][lr][0] = bh0;
        *(int4*)&Bh[2*h+1][lr][0] = bh1;
        *(int4*)&Bl[2*h  ][lr][0] = bl0;
        *(int4*)&Bl[2*h+1][lr][0] = bl1;
        __syncthreads();

        half8 fah[4], fal[4], fbh[4], fbl[4];
#pragma unroll
        for (int t = 0; t < 4; ++t) {
            fah[t] = *(const half8*)&Ah[quad][mw*64 + t*16 + l15][0];
            fal[t] = *(const half8*)&Al[quad][mw*64 + t*16 + l15][0];
            fbh[t] = *(const half8*)&Bh[quad][nw*64 + t*16 + l15][0];
            fbl[t] = *(const half8*)&Bl[quad][nw*64 + t*16 + l15][0];
        }
#pragma unroll
        for (int ti = 0; ti < 4; ++ti)
#pragma unroll
            for (int tj = 0; tj < 4; ++tj) {
                accA[ti][tj] = __builtin_amdgcn_mfma_f32_16x16x32_f16(fah[ti], fbh[tj], accA[ti][tj], 0, 0, 0);
                accB[ti][tj] = __builtin_amdgcn_mfma_f32_16x16x32_f16(fah[ti], fbl[tj], accB[ti][tj], 0, 0, 0);
                accB[ti][tj] = __builtin_amdgcn_mfma_f32_16x16x32_f16(fal[ti], fbh[tj], accB[ti][tj], 0, 0, 0);
            }
    }

#pragma unroll
    for (int tj = 0; tj < 4; ++tj) {
        const int o = bn*128 + nw*64 + tj*16 + l15;
        const float alpha = ab[o], beta = ab[256 + o];
#pragma unroll
        for (int ti = 0; ti < 4; ++ti) {
            const int m0 = bm*128 + mw*64 + ti*16 + quad*4;
#pragma unroll
            for (int r = 0; r < 4; ++r) {
                float c = accA[ti][tj][r] + accB[ti][tj][r] * (1.0f/2048.0f);
                float z = c * alpha + beta;
                _Float16 zh, zl;
                split_f32(z, zh, zl);
                const size_t off = (size_t)(m0 + r) * 256 + o;
                z1h[off] = zh;
                z1l[off] = zl;
            }
        }
    }
}

// ---------------------------------------------------------------------------
// K2: conv2 + bn2, fp16 2-limb MFMA GEMM. K=768 (dt*256+c), halo zero-fill.
// (unchanged from R3 — passed)
// ---------------------------------------------------------------------------
__global__ __launch_bounds__(256, 2) void conv2_mfma(
    const _Float16* __restrict__ z1h, const _Float16* __restrict__ z1l,
    const _Float16* __restrict__ w2h, const _Float16* __restrict__ w2l,
    const float* __restrict__ ab, float* __restrict__ z2)
{
    __shared__ _Float16 Ah[4][128][8];
    __shared__ _Float16 Al[4][128][8];
    __shared__ _Float16 Bh[4][128][8];
    __shared__ _Float16 Bl[4][128][8];

    const int tid = threadIdx.x;
    const int bm = blockIdx.x, bn = blockIdx.y;
    const int lr = tid & 127;
    const int h  = tid >> 7;

    const int am = bm * 128 + lr;
    const int an = am / 63, at = am - an * 63;
    const _Float16* abase_h = z1h + (size_t)an * 16128;
    const _Float16* abase_l = z1l + (size_t)an * 16128;
    const _Float16* bhrow = w2h + (size_t)(bn * 128 + lr) * 768 + h * 16;
    const _Float16* blrow = w2l + (size_t)(bn * 128 + lr) * 768 + h * 16;

    const int lane = tid & 63;
    const int wv   = tid >> 6;
    const int mw   = wv & 1, nw = wv >> 1;
    const int quad = lane >> 4;
    const int l15  = lane & 15;

    floatx4 accA[4][4] = {};
    floatx4 accB[4][4] = {};

    const int4 z4 = {0, 0, 0, 0};

    for (int it = 0; it < 24; ++it) {
        const int kap0 = it * 32;
        const int dt   = kap0 >> 8;
        const int c0   = kap0 & 255;
        const int trow = at + dt - 1;
        const bool valid = (trow >= 0) && (trow < 63);
        const _Float16* aph = abase_h + trow * 256 + c0 + h * 16;
        const _Float16* apl = abase_l + trow * 256 + c0 + h * 16;
        int4 a0h = valid ? *(const int4*)(aph)     : z4;
        int4 a1h = valid ? *(const int4*)(aph + 8) : z4;
        int4 a0l = valid ? *(const int4*)(apl)     : z4;
        int4 a1l = valid ? *(const int4*)(apl + 8) : z4;
        int4 b0h = *(const int4*)(bhrow + kap0);
        int4 b1h = *(const int4*)(bhrow + kap0 + 8);
        int4 b0l = *(const int4*)(blrow + kap0);
        int4 b1l = *(const int4*)(blrow + kap0 + 8);

        __syncthreads();
        *(int4*)&Ah[2*h  ][lr][0] = a0h;
        *(int4*)&Ah[2*h+1][lr][0] = a1h;
        *(int4*)&Al[2*h  ][lr][0] = a0l;
        *(int4*)&Al[2*h+1][lr][0] = a1l;
        *(int4*)&Bh[2*h  ][lr][0] = b0h;
        *(int4*)&Bh[2*h+1][lr][0] = b1h;
        *(int4*)&Bl[2*h  ][lr][0] = b0l;
        *(int4*)&Bl[2*h+1][lr][0] = b1l;
        __syncthreads();

        half8 fah[4], fal[4], fbh[4], fbl[4];
#pragma unroll
        for (int t = 0; t < 4; ++t) {
            fah[t] = *(const half8*)&Ah[quad][mw*64 + t*16 + l15][0];
            fal[t] = *(const half8*)&Al[quad][mw*64 + t*16 + l15][0];
            fbh[t] = *(const half8*)&Bh[quad][nw*64 + t*16 + l15][0];
            fbl[t] = *(const half8*)&Bl[quad][nw*64 + t*16 + l15][0];
        }
#pragma unroll
        for (int ti = 0; ti < 4; ++ti)
#pragma unroll
            for (int tj = 0; tj < 4; ++tj) {
                accA[ti][tj] = __builtin_amdgcn_mfma_f32_16x16x32_f16(fah[ti], fbh[tj], accA[ti][tj], 0, 0, 0);
                accB[ti][tj] = __builtin_amdgcn_mfma_f32_16x16x32_f16(fah[ti], fbl[tj], accB[ti][tj], 0, 0, 0);
                accB[ti][tj] = __builtin_amdgcn_mfma_f32_16x16x32_f16(fal[ti], fbh[tj], accB[ti][tj], 0, 0, 0);
            }
    }

#pragma unroll
    for (int tj = 0; tj < 4; ++tj) {
        const int o = bn*128 + nw*64 + tj*16 + l15;
        const float alpha = ab[o], beta = ab[256 + o];
#pragma unroll
        for (int ti = 0; ti < 4; ++ti) {
            const int m0 = bm*128 + mw*64 + ti*16 + quad*4;
#pragma unroll
            for (int r = 0; r < 4; ++r) {
                float c = accA[ti][tj][r] + accB[ti][tj][r] * (1.0f/2048.0f);
                z2[(size_t)(m0 + r) * 256 + o] = c * alpha + beta;
            }
        }
    }
}

// ---------------------------------------------------------------------------
// K3a: cuba1 — z2 [n][t][c] -> binary spikes s1 (fp16 {0,1}) in [n][t][c]
// thread = (n=block, c=tid); sequential over t; coalesced reads & writes.
// ---------------------------------------------------------------------------
__global__ __launch_bounds__(256) void cuba1_kernel(
    const float* __restrict__ z2, _Float16* __restrict__ s1)
{
    const int n   = blockIdx.x;
    const int tid = threadIdx.x;
    const float* zrow = z2 + (size_t)n * 16128 + tid;
    _Float16*    srow = s1 + (size_t)n * 16128 + tid;
    float cur = 0.f, vol = 0.f;
    for (int t = 0; t < 63; ++t) {
        float xv = zrow[(size_t)t * 256];
        cur = 0.1f * cur + xv;
        vol = 0.1f * vol + cur;
        bool sp = (vol - 0.3f) >= 0.f;
        srow[(size_t)t * 256] = sp ? (_Float16)1.0f : (_Float16)0.0f;
        if (sp) vol = 0.f;
    }
}

// ---------------------------------------------------------------------------
// K3b: dense1 via MFMA. y1[n*63+t][o] = sum_c s1[row][c] * w1[o][c].
// M=32256, K=256, N=256. A exact binary fp16 (1 limb), B 2-limb.
// ---------------------------------------------------------------------------
__global__ __launch_bounds__(256, 2) void dense1_mfma(
    const _Float16* __restrict__ s1,
    const _Float16* __restrict__ wdh, const _Float16* __restrict__ wdl,
    float* __restrict__ y1)
{
    __shared__ _Float16 As[4][128][8];
    __shared__ _Float16 Bh[4][128][8];
    __shared__ _Float16 Bl[4][128][8];

    const int tid = threadIdx.x;
    const int bm = blockIdx.x, bn = blockIdx.y;
    const int lr = tid & 127;
    const int h  = tid >> 7;

    const _Float16* arow  = s1  + (size_t)(bm * 128 + lr) * 256 + h * 16;
    const _Float16* bhrow = wdh + (size_t)(bn * 128 + lr) * 256 + h * 16;
    const _Float16* blrow = wdl + (size_t)(bn * 128 + lr) * 256 + h * 16;

    const int lane = tid & 63;
    const int wv   = tid >> 6;
    const int mw   = wv & 1, nw = wv >> 1;
    const int quad = lane >> 4;
    const int l15  = lane & 15;

    floatx4 accA[4][4] = {};
    floatx4 accB[4][4] = {};

    for (int it = 0; it < 8; ++it) {
        const int kap0 = it * 32;
        int4 a0 = *(const int4*)(arow + kap0);
        int4 a1 = *(const int4*)(arow + kap0 + 8);
        int4 b0h = *(const int4*)(bhrow + kap0);
        int4 b1h = *(const int4*)(bhrow + kap0 + 8);
        int4 b0l = *(const int4*)(blrow + kap0);
        int4 b1l = *(const int4*)(blrow + kap0 + 8);

        __syncthreads();
        *(int4*)&As[2*h  ][lr][0] = a0;
        *(int4*)&As[2*h+1][lr][0] = a1;
        *(int4*)&Bh[2*h  ][lr][0] = b0h;
        *(int4*)&Bh[2*h+1][lr][0] = b1h;
        *(int4*)&Bl[2*h  ][lr][0] = b0l;
        *(int4*)&Bl[2*h+1][lr][0] = b1l;
        __syncthreads();

        half8 fa[4], fbh[4], fbl[4];
#pragma unroll
        for (int t = 0; t < 4; ++t) {
            fa[t]  = *(const half8*)&As[quad][mw*64 + t*16 + l15][0];
            fbh[t] = *(const half8*)&Bh[quad][nw*64 + t*16 + l15][0];
            fbl[t] = *(const half8*)&Bl[quad][nw*64 + t*16 + l15][0];
        }
#pragma unroll
        for (int ti = 0; ti < 4; ++ti)
#pragma unroll
            for (int tj = 0; tj < 4; ++tj) {
                accA[ti][tj] = __builtin_amdgcn_mfma_f32_16x16x32_f16(fa[ti], fbh[tj], accA[ti][tj], 0, 0, 0);
                accB[ti][tj] = __builtin_amdgcn_mfma_f32_16x16x32_f16(fa[ti], fbl[tj], accB[ti][tj], 0, 0, 0);
            }
    }

#pragma unroll
    for (int tj = 0; tj < 4; ++tj) {
        const int o = bn*128 + nw*64 + tj*16 + l15;
#pragma unroll
        for (int ti = 0; ti < 4; ++ti) {
            const int m0 = bm*128 + mw*64 + ti*16 + quad*4;
#pragma unroll
            for (int r = 0; r < 4; ++r)
                y1[(size_t)(m0 + r) * 256 + o] =
                    accA[ti][tj][r] + accB[ti][tj][r] * (1.0f/2048.0f);
        }
    }
}

// ---------------------------------------------------------------------------
// K3c: cuba2 (per (n,o) over t) -> spike masks -> dense2 -> cuba3 -> out
// ---------------------------------------------------------------------------
__global__ __launch_bounds__(256) void snn_tail(
    const float* __restrict__ y1, const float* __restrict__ w2,
    float* __restrict__ out)
{
    __shared__ unsigned long long M2[256];
    __shared__ float Y[2 * 63];
    const int n   = blockIdx.x;
    const int tid = threadIdx.x;

    // cuba2: thread = output channel o, reads y1[n][t][o] coalesced
    {
        const float* yrow = y1 + (size_t)n * 16128 + tid;
        float v = 0.f;
        unsigned long long mask2 = 0ull;
        for (int t = 0; t < 63; ++t) {
            float yv = yrow[(size_t)t * 256];
            v = 0.9f * v + yv;                 // cd=0 -> i = x
            if ((v - 0.1f) >= 0.f) { mask2 |= (1ull << t); v = 0.f; }
        }
        M2[tid] = mask2;
    }
    __syncthreads();

    if (tid < 126) {
        const int cls = tid / 63;
        const int t   = tid - cls * 63;
        const float* wrow = w2 + cls * 256;
        float acc = 0.f;
#pragma unroll 4
        for (int o = 0; o < 256; ++o)
            acc += ((M2[o] >> t) & 1ull) ? wrow[o] : 0.f;
        Y[cls * 63 + t] = acc;
    }
    __syncthreads();
    if (tid < 2) {
        float v = 0.f;
        float* orow = out + (size_t)n * 126 + tid * 63;
        for (int t = 0; t < 63; ++t) {
            v = 0.9f * v + Y[tid * 63 + t];
            float u = v - 0.1f;
            float s = (u >= 0.f) ? 1.f : 0.f;
            orow[t] = s;
            v = (u >= 0.f) ? 0.f : v;
        }
    }
}

// ---------------------------------------------------------------------------
extern "C" void kernel_launch(void* const* d_in, const int* in_sizes, int n_in,
                              void* d_out, int out_size, void* d_ws, size_t ws_size,
                              hipStream_t stream)
{
    const float* x    = (const float*)d_in[0];
    const float* c1w  = (const float*)d_in[1];
    const float* c1b  = (const float*)d_in[2];
    const float* g1   = (const float*)d_in[3];
    const float* b1   = (const float*)d_in[4];
    const float* m1   = (const float*)d_in[5];
    const float* v1   = (const float*)d_in[6];
    const float* c2w  = (const float*)d_in[7];
    const float* c2b  = (const float*)d_in[8];
    const float* g2   = (const float*)d_in[9];
    const float* b2   = (const float*)d_in[10];
    const float* m2   = (const float*)d_in[11];
    const float* v2   = (const float*)d_in[12];
    const float* w1   = (const float*)d_in[13];
    const float* w2   = (const float*)d_in[14];
    float* out = (float*)d_out;

    float* ws = (float*)d_ws;
    // region A: z1 limbs during conv; reused as y1 (fp32) after conv2
    float*    zA  = ws;                               // 8,257,536 f
    _Float16* z1h = (_Float16*)zA;
    _Float16* z1l = (_Float16*)(zA + 4128768);
    float*    y1  = zA;
    float*    z2  = zA + 8257536;                     // 8,257,536 f
    _Float16* s1  = (_Float16*)(z2 + 8257536);        // 4,128,768 f
    float*    wsp = z2 + 8257536 + 4128768;
    _Float16* w1h = (_Float16*)wsp;                   // 262,144 f
    _Float16* w1l = (_Float16*)(wsp + 262144);        // 262,144 f
    _Float16* w2h = (_Float16*)(wsp + 2*262144);                    //  98,304 f
    _Float16* w2l = (_Float16*)(wsp + 2*262144 + 98304);            //  98,304 f
    _Float16* wdh = (_Float16*)(wsp + 2*262144 + 2*98304);          //  32,768 f
    _Float16* wdl = (_Float16*)(wsp + 2*262144 + 2*98304 + 32768);  //  32,768 f
    float*    ab1 = wsp + 2*262144 + 2*98304 + 2*32768;
    float*    ab2 = ab1 + 512;

    prep_kernel<<<256, 256, 0, stream>>>(c1w, c1b, g1, b1, m1, v1,
                                         c2w, c2b, g2, b2, m2, v2,
                                         w1, w1h, w1l, w2h, w2l, wdh, wdl,
                                         ab1, ab2);
    conv1_mfma<<<dim3(252, 2), 256, 0, stream>>>(x, w1h, w1l, ab1, z1h, z1l);
    conv2_mfma<<<dim3(252, 2), 256, 0, stream>>>(z1h, z1l, w2h, w2l, ab2, z2);
    cuba1_kernel<<<512, 256, 0, stream>>>(z2, s1);
    dense1_mfma<<<dim3(252, 2), 256, 0, stream>>>(s1, wdh, wdl, y1);
    snn_tail<<<512, 256, 0, stream>>>(y1, w2, out);
}